// Round 1
// baseline (665.140 us; speedup 1.0000x reference)
//
#include <hip/hip_runtime.h>
#include <math.h>

#define Bn 16
#define Sn 8192
#define Dn 512
#define CHUNKS 64
#define TOK_PER_BLOCK (Sn / CHUNKS)      // 128 tokens per block
#define TOK_PER_WAVE (TOK_PER_BLOCK / 4) // 32 tokens per wave (4 waves/block)

// ---------------------------------------------------------------------------
// K1: per-token L2 norm (f64) -> inv_norm; accumulate hsum[b] = sum_s h[b,s] (f64)
// ---------------------------------------------------------------------------
__global__ __launch_bounds__(256) void k1_norm_hsum(
    const float* __restrict__ hidden, double* __restrict__ inv_norm,
    double* __restrict__ hsum) {
  __shared__ double lds[Dn];
  const int b = blockIdx.x / CHUNKS;
  const int chunk = blockIdx.x % CHUNKS;
  const int wave = threadIdx.x >> 6;
  const int lane = threadIdx.x & 63;
  for (int i = threadIdx.x; i < Dn; i += 256) lds[i] = 0.0;
  __syncthreads();

  double acc[8] = {0., 0., 0., 0., 0., 0., 0., 0.};
  const int sbase = chunk * TOK_PER_BLOCK + wave * TOK_PER_WAVE;
  for (int t = 0; t < TOK_PER_WAVE; ++t) {
    const int s = sbase + t;
    const size_t tok = (size_t)b * Sn + s;
    const float4* row = (const float4*)(hidden + tok * Dn);
    float4 a = row[lane];
    float4 c = row[64 + lane];
    double ss = (double)a.x * a.x + (double)a.y * a.y + (double)a.z * a.z +
                (double)a.w * a.w + (double)c.x * c.x + (double)c.y * c.y +
                (double)c.z * c.z + (double)c.w * c.w;
#pragma unroll
    for (int m = 32; m >= 1; m >>= 1) ss += __shfl_xor(ss, m, 64);
    double nrm = sqrt(ss);
    if (nrm < 1e-12) nrm = 1e-12;
    const double inv = 1.0 / nrm;
    if (lane == 0) inv_norm[tok] = inv;
    acc[0] += (double)a.x * inv; acc[1] += (double)a.y * inv;
    acc[2] += (double)a.z * inv; acc[3] += (double)a.w * inv;
    acc[4] += (double)c.x * inv; acc[5] += (double)c.y * inv;
    acc[6] += (double)c.z * inv; acc[7] += (double)c.w * inv;
  }
  const int d0 = lane * 4;
  atomicAdd(&lds[d0 + 0], acc[0]);
  atomicAdd(&lds[d0 + 1], acc[1]);
  atomicAdd(&lds[d0 + 2], acc[2]);
  atomicAdd(&lds[d0 + 3], acc[3]);
  atomicAdd(&lds[256 + d0 + 0], acc[4]);
  atomicAdd(&lds[256 + d0 + 1], acc[5]);
  atomicAdd(&lds[256 + d0 + 2], acc[6]);
  atomicAdd(&lds[256 + d0 + 3], acc[7]);
  __syncthreads();
  for (int i = threadIdx.x; i < Dn; i += 256)
    atomicAdd(&hsum[b * Dn + i], lds[i]);
}

// ---------------------------------------------------------------------------
// K2: per-batch u[b] = Wq^T * (Wk * hsum[b])   (all f64)
// ---------------------------------------------------------------------------
__global__ __launch_bounds__(512) void k2_u(
    const float* __restrict__ Wq, const float* __restrict__ Wk,
    const double* __restrict__ hsum, double* __restrict__ u) {
  __shared__ double hl[Dn];
  __shared__ double ks[Dn];
  const int b = blockIdx.x;
  for (int i = threadIdx.x; i < Dn; i += 512) hl[i] = hsum[b * Dn + i];
  __syncthreads();
  const int wave = threadIdx.x >> 6, lane = threadIdx.x & 63;
  for (int dd = 0; dd < 64; ++dd) {
    const int d = wave * 64 + dd;
    double acc = 0.0;
#pragma unroll
    for (int k = 0; k < 8; ++k) {
      const int e = lane + 64 * k;
      acc += (double)Wk[d * Dn + e] * hl[e];  // coalesced row read
    }
#pragma unroll
    for (int m = 32; m >= 1; m >>= 1) acc += __shfl_xor(acc, m, 64);
    if (lane == 0) ks[d] = acc;
  }
  __syncthreads();
  const int e = threadIdx.x;  // 512 threads = 512 outputs
  double acc = 0.0;
  for (int d = 0; d < Dn; ++d) acc += (double)Wq[d * Dn + e] * ks[d];  // coalesced
  u[b * Dn + e] = acc;
}

// ---------------------------------------------------------------------------
// K3: scores (f64) + keep decision
// keep = sigmoid(score + log(noise) - log1p(-noise)) > 0.5  <=>  arg > 0
// ---------------------------------------------------------------------------
__global__ __launch_bounds__(256) void k3_scores(
    const float* __restrict__ hidden, const double* __restrict__ inv_norm,
    const double* __restrict__ u, const float* __restrict__ noise,
    int* __restrict__ keep) {
  __shared__ double ul[Dn];
  const int b = blockIdx.x / CHUNKS;
  const int chunk = blockIdx.x % CHUNKS;
  for (int i = threadIdx.x; i < Dn; i += 256) ul[i] = u[b * Dn + i];
  __syncthreads();
  const int wave = threadIdx.x >> 6, lane = threadIdx.x & 63;
  const int sbase = chunk * TOK_PER_BLOCK + wave * TOK_PER_WAVE;
  for (int t = 0; t < TOK_PER_WAVE; ++t) {
    const int s = sbase + t;
    const size_t tok = (size_t)b * Sn + s;
    const float4* row = (const float4*)(hidden + tok * Dn);
    float4 a = row[lane], c = row[64 + lane];
    const int d0 = lane * 4;
    double dot = (double)a.x * ul[d0 + 0] + (double)a.y * ul[d0 + 1] +
                 (double)a.z * ul[d0 + 2] + (double)a.w * ul[d0 + 3] +
                 (double)c.x * ul[256 + d0 + 0] + (double)c.y * ul[256 + d0 + 1] +
                 (double)c.z * ul[256 + d0 + 2] + (double)c.w * ul[256 + d0 + 3];
#pragma unroll
    for (int m = 32; m >= 1; m >>= 1) dot += __shfl_xor(dot, m, 64);
    if (lane == 0) {
      double x = 0.125 * inv_norm[tok] * dot;  // SCALE = 64^-0.5 = 1/8
      const double nv = (double)noise[tok];
      x += log(nv) - log1p(-nv);
      keep[tok] = (x > 0.0) ? 1 : 0;
    }
  }
}

// ---------------------------------------------------------------------------
// K4: per-batch stable exclusive prefix sum of keep -> pos, counts, binomial logprob
// ---------------------------------------------------------------------------
__global__ __launch_bounds__(1024) void k4_scan(
    const int* __restrict__ keep, int* __restrict__ pos,
    int* __restrict__ counts, double* __restrict__ logprob) {
  __shared__ int lds[1024];
  const int b = blockIdx.x, tid = threadIdx.x;
  const size_t base = (size_t)b * Sn + (size_t)tid * 8;
  int v[8], pref[8], tot = 0;
#pragma unroll
  for (int j = 0; j < 8; ++j) {
    v[j] = keep[base + j];
    pref[j] = tot;
    tot += v[j];
  }
  lds[tid] = tot;
  __syncthreads();
  for (int off = 1; off < 1024; off <<= 1) {
    const int val = (tid >= off) ? lds[tid - off] : 0;
    __syncthreads();
    lds[tid] += val;
    __syncthreads();
  }
  const int excl = lds[tid] - tot;
#pragma unroll
  for (int j = 0; j < 8; ++j) pos[base + j] = excl + pref[j];
  if (tid == 1023) {
    const int cnt = lds[1023];
    counts[b] = cnt;
    const double n = (double)Sn, k = (double)cnt;
    logprob[b] = lgamma(n + 1.0) - lgamma(k + 1.0) - lgamma(n - k + 1.0) +
                 k * log(0.2) + (n - k) * log1p(-0.2);
  }
}

// ---------------------------------------------------------------------------
// K5: scatter kept rows h = hidden*inv_norm to out[b,pos]; zero rows >= count;
//     write loss scalar at out[B*S*D]
// ---------------------------------------------------------------------------
__global__ __launch_bounds__(256) void k5_scatter(
    const float* __restrict__ hidden, const double* __restrict__ inv_norm,
    const int* __restrict__ keep, const int* __restrict__ pos,
    const int* __restrict__ counts, const double* __restrict__ logprob,
    float* __restrict__ out) {
  const int b = blockIdx.x / CHUNKS;
  const int chunk = blockIdx.x % CHUNKS;
  const int wave = threadIdx.x >> 6, lane = threadIdx.x & 63;
  const int cnt = counts[b];
  const int sbase = chunk * TOK_PER_BLOCK + wave * TOK_PER_WAVE;
  for (int t = 0; t < TOK_PER_WAVE; ++t) {
    const int s = sbase + t;
    const size_t tok = (size_t)b * Sn + s;
    if (s >= cnt) {
      float4* orow = (float4*)(out + tok * Dn);
      const float4 z = make_float4(0.f, 0.f, 0.f, 0.f);
      orow[lane] = z;
      orow[64 + lane] = z;
    }
    if (keep[tok]) {
      const int p = pos[tok];
      const double inv = inv_norm[tok];
      const float4* row = (const float4*)(hidden + tok * Dn);
      float4 a = row[lane], c = row[64 + lane];
      a.x = (float)((double)a.x * inv); a.y = (float)((double)a.y * inv);
      a.z = (float)((double)a.z * inv); a.w = (float)((double)a.w * inv);
      c.x = (float)((double)c.x * inv); c.y = (float)((double)c.y * inv);
      c.z = (float)((double)c.z * inv); c.w = (float)((double)c.w * inv);
      float4* orow = (float4*)(out + ((size_t)b * Sn + p) * Dn);
      orow[lane] = a;
      orow[64 + lane] = c;
    }
  }
  if (blockIdx.x == 0 && threadIdx.x == 0) {
    double sm = 0.0;
    for (int i = 0; i < Bn; ++i) sm += logprob[i];
    out[(size_t)Bn * Sn * Dn] = (float)(-(sm / (double)Bn) / (double)Sn);
  }
}

// ---------------------------------------------------------------------------
extern "C" void kernel_launch(void* const* d_in, const int* in_sizes, int n_in,
                              void* d_out, int out_size, void* d_ws, size_t ws_size,
                              hipStream_t stream) {
  const float* hidden = (const float*)d_in[0];
  const float* Wq = (const float*)d_in[1];
  const float* Wk = (const float*)d_in[2];
  const float* noise = (const float*)d_in[3];
  float* out = (float*)d_out;

  char* ws = (char*)d_ws;
  // ws layout (all 8-byte aligned)
  double* hsum = (double*)(ws);                               // 16*512*8   = 65536
  double* u = (double*)(ws + 65536);                          // 65536
  double* inv_nrm = (double*)(ws + 131072);                   // 16*8192*8  = 1048576
  int* keep = (int*)(ws + 131072 + 1048576);                  // 16*8192*4  = 524288
  int* pos = (int*)(ws + 131072 + 1048576 + 524288);          // 524288
  int* counts = (int*)(ws + 131072 + 1048576 + 2 * 524288);   // 64 (pad 256)
  double* logprob = (double*)(ws + 131072 + 1048576 + 2 * 524288 + 256);  // 128

  hipMemsetAsync(hsum, 0, Bn * Dn * sizeof(double), stream);

  k1_norm_hsum<<<Bn * CHUNKS, 256, 0, stream>>>(hidden, inv_nrm, hsum);
  k2_u<<<Bn, 512, 0, stream>>>(Wq, Wk, hsum, u);
  k3_scores<<<Bn * CHUNKS, 256, 0, stream>>>(hidden, inv_nrm, u, noise, keep);
  k4_scan<<<Bn, 1024, 0, stream>>>(keep, pos, counts, logprob);
  k5_scatter<<<Bn * CHUNKS, 256, 0, stream>>>(hidden, inv_nrm, keep, pos, counts,
                                              logprob, out);
}

// Round 2
// 605.507 us; speedup vs baseline: 1.0985x; 1.0985x over previous
//
#include <hip/hip_runtime.h>
#include <math.h>

#define Bn 16
#define Sn 8192
#define Dn 512
#define CHUNKS 64
#define TOK_PER_BLOCK (Sn / CHUNKS)      // 128 tokens per block
#define TOK_PER_WAVE (TOK_PER_BLOCK / 4) // 32 tokens per wave (4 waves/block)

__device__ __forceinline__ double dot8sq(const float4& a, const float4& c) {
  return (double)a.x * a.x + (double)a.y * a.y + (double)a.z * a.z +
         (double)a.w * a.w + (double)c.x * c.x + (double)c.y * c.y +
         (double)c.z * c.z + (double)c.w * c.w;
}

// ---------------------------------------------------------------------------
// K1: per-token L2 norm (f64) -> inv_norm; hsum[b] = sum_s h[b,s] (f64)
// 4 tokens in flight per wave iteration; no LDS atomics.
// ---------------------------------------------------------------------------
__global__ __launch_bounds__(256) void k1_norm_hsum(
    const float* __restrict__ hidden, double* __restrict__ inv_norm,
    double* __restrict__ hsum) {
  __shared__ double part[4][Dn];  // 16 KB
  const int b = blockIdx.x / CHUNKS;
  const int chunk = blockIdx.x % CHUNKS;
  const int wave = threadIdx.x >> 6;
  const int lane = threadIdx.x & 63;

  double acc[8] = {0., 0., 0., 0., 0., 0., 0., 0.};
  const int sbase = chunk * TOK_PER_BLOCK + wave * TOK_PER_WAVE;
  const float* hb = hidden + (size_t)b * Sn * Dn;

  for (int t0 = 0; t0 < TOK_PER_WAVE; t0 += 4) {
    const int s = sbase + t0;
    const float4* r0 = (const float4*)(hb + (size_t)(s + 0) * Dn);
    const float4* r1 = (const float4*)(hb + (size_t)(s + 1) * Dn);
    const float4* r2 = (const float4*)(hb + (size_t)(s + 2) * Dn);
    const float4* r3 = (const float4*)(hb + (size_t)(s + 3) * Dn);
    float4 a0 = r0[lane], c0 = r0[64 + lane];
    float4 a1 = r1[lane], c1 = r1[64 + lane];
    float4 a2 = r2[lane], c2 = r2[64 + lane];
    float4 a3 = r3[lane], c3 = r3[64 + lane];
    double s0 = dot8sq(a0, c0), s1 = dot8sq(a1, c1);
    double s2 = dot8sq(a2, c2), s3 = dot8sq(a3, c3);
#pragma unroll
    for (int m = 32; m >= 1; m >>= 1) {
      s0 += __shfl_xor(s0, m, 64);
      s1 += __shfl_xor(s1, m, 64);
      s2 += __shfl_xor(s2, m, 64);
      s3 += __shfl_xor(s3, m, 64);
    }
    const double i0 = 1.0 / fmax(sqrt(s0), 1e-12);
    const double i1 = 1.0 / fmax(sqrt(s1), 1e-12);
    const double i2 = 1.0 / fmax(sqrt(s2), 1e-12);
    const double i3 = 1.0 / fmax(sqrt(s3), 1e-12);
    if (lane < 4) {
      const double iv = (lane == 0) ? i0 : (lane == 1) ? i1 : (lane == 2) ? i2 : i3;
      inv_norm[(size_t)b * Sn + s + lane] = iv;
    }
    acc[0] += (double)a0.x * i0 + (double)a1.x * i1 + (double)a2.x * i2 + (double)a3.x * i3;
    acc[1] += (double)a0.y * i0 + (double)a1.y * i1 + (double)a2.y * i2 + (double)a3.y * i3;
    acc[2] += (double)a0.z * i0 + (double)a1.z * i1 + (double)a2.z * i2 + (double)a3.z * i3;
    acc[3] += (double)a0.w * i0 + (double)a1.w * i1 + (double)a2.w * i2 + (double)a3.w * i3;
    acc[4] += (double)c0.x * i0 + (double)c1.x * i1 + (double)c2.x * i2 + (double)c3.x * i3;
    acc[5] += (double)c0.y * i0 + (double)c1.y * i1 + (double)c2.y * i2 + (double)c3.y * i3;
    acc[6] += (double)c0.z * i0 + (double)c1.z * i1 + (double)c2.z * i2 + (double)c3.z * i3;
    acc[7] += (double)c0.w * i0 + (double)c1.w * i1 + (double)c2.w * i2 + (double)c3.w * i3;
  }
  const int d0 = lane * 4;
#pragma unroll
  for (int k = 0; k < 4; ++k) {
    part[wave][d0 + k] = acc[k];
    part[wave][256 + d0 + k] = acc[4 + k];
  }
  __syncthreads();
  for (int i = threadIdx.x; i < Dn; i += 256) {
    const double v = part[0][i] + part[1][i] + part[2][i] + part[3][i];
    atomicAdd(&hsum[b * Dn + i], v);
  }
}

// ---------------------------------------------------------------------------
// K2: per-batch u[b] = Wq^T * (Wk * hsum[b])  (f64), thread-per-output
// ---------------------------------------------------------------------------
__global__ __launch_bounds__(512) void k2_u(
    const float* __restrict__ Wq, const float* __restrict__ Wk,
    const double* __restrict__ hsum, double* __restrict__ u) {
  __shared__ double hl[Dn];
  __shared__ double ks[Dn];
  const int b = blockIdx.x;
  const int tid = threadIdx.x;
  hl[tid] = hsum[b * Dn + tid];
  __syncthreads();
  {
    const float* wrow = Wk + (size_t)tid * Dn;
    double p0 = 0., p1 = 0., p2 = 0., p3 = 0.;
    for (int e = 0; e < Dn; e += 4) {
      p0 += (double)wrow[e + 0] * hl[e + 0];
      p1 += (double)wrow[e + 1] * hl[e + 1];
      p2 += (double)wrow[e + 2] * hl[e + 2];
      p3 += (double)wrow[e + 3] * hl[e + 3];
    }
    ks[tid] = (p0 + p1) + (p2 + p3);
  }
  __syncthreads();
  {
    double p0 = 0., p1 = 0., p2 = 0., p3 = 0.;
    for (int d = 0; d < Dn; d += 4) {
      p0 += (double)Wq[(size_t)(d + 0) * Dn + tid] * ks[d + 0];
      p1 += (double)Wq[(size_t)(d + 1) * Dn + tid] * ks[d + 1];
      p2 += (double)Wq[(size_t)(d + 2) * Dn + tid] * ks[d + 2];
      p3 += (double)Wq[(size_t)(d + 3) * Dn + tid] * ks[d + 3];
    }
    u[b * Dn + tid] = (p0 + p1) + (p2 + p3);
  }
}

// ---------------------------------------------------------------------------
// K3: scores (f64) + keep decision; u hoisted to registers; 4 tokens/iter
// ---------------------------------------------------------------------------
__global__ __launch_bounds__(256) void k3_scores(
    const float* __restrict__ hidden, const double* __restrict__ inv_norm,
    const double* __restrict__ u, const float* __restrict__ noise,
    int* __restrict__ keep) {
  __shared__ double ul[Dn];
  const int b = blockIdx.x / CHUNKS;
  const int chunk = blockIdx.x % CHUNKS;
  for (int i = threadIdx.x; i < Dn; i += 256) ul[i] = u[b * Dn + i];
  __syncthreads();
  const int wave = threadIdx.x >> 6, lane = threadIdx.x & 63;
  const int d0 = lane * 4;
  const double u0 = ul[d0 + 0], u1 = ul[d0 + 1], u2 = ul[d0 + 2], u3 = ul[d0 + 3];
  const double u4 = ul[256 + d0 + 0], u5 = ul[256 + d0 + 1];
  const double u6 = ul[256 + d0 + 2], u7 = ul[256 + d0 + 3];
  const int sbase = chunk * TOK_PER_BLOCK + wave * TOK_PER_WAVE;
  const float* hb = hidden + (size_t)b * Sn * Dn;

  for (int t0 = 0; t0 < TOK_PER_WAVE; t0 += 4) {
    const int s = sbase + t0;
    const float4* r0 = (const float4*)(hb + (size_t)(s + 0) * Dn);
    const float4* r1 = (const float4*)(hb + (size_t)(s + 1) * Dn);
    const float4* r2 = (const float4*)(hb + (size_t)(s + 2) * Dn);
    const float4* r3 = (const float4*)(hb + (size_t)(s + 3) * Dn);
    float4 a0 = r0[lane], c0 = r0[64 + lane];
    float4 a1 = r1[lane], c1 = r1[64 + lane];
    float4 a2 = r2[lane], c2 = r2[64 + lane];
    float4 a3 = r3[lane], c3 = r3[64 + lane];
    double d0v = (double)a0.x * u0 + (double)a0.y * u1 + (double)a0.z * u2 + (double)a0.w * u3 +
                 (double)c0.x * u4 + (double)c0.y * u5 + (double)c0.z * u6 + (double)c0.w * u7;
    double d1v = (double)a1.x * u0 + (double)a1.y * u1 + (double)a1.z * u2 + (double)a1.w * u3 +
                 (double)c1.x * u4 + (double)c1.y * u5 + (double)c1.z * u6 + (double)c1.w * u7;
    double d2v = (double)a2.x * u0 + (double)a2.y * u1 + (double)a2.z * u2 + (double)a2.w * u3 +
                 (double)c2.x * u4 + (double)c2.y * u5 + (double)c2.z * u6 + (double)c2.w * u7;
    double d3v = (double)a3.x * u0 + (double)a3.y * u1 + (double)a3.z * u2 + (double)a3.w * u3 +
                 (double)c3.x * u4 + (double)c3.y * u5 + (double)c3.z * u6 + (double)c3.w * u7;
#pragma unroll
    for (int m = 32; m >= 1; m >>= 1) {
      d0v += __shfl_xor(d0v, m, 64);
      d1v += __shfl_xor(d1v, m, 64);
      d2v += __shfl_xor(d2v, m, 64);
      d3v += __shfl_xor(d3v, m, 64);
    }
    if (lane < 4) {
      const double dj = (lane == 0) ? d0v : (lane == 1) ? d1v : (lane == 2) ? d2v : d3v;
      const size_t tok = (size_t)b * Sn + s + lane;
      const double nv = (double)noise[tok];
      const double x = 0.125 * inv_norm[tok] * dj + log(nv) - log1p(-nv);
      keep[tok] = (x > 0.0) ? 1 : 0;
    }
  }
}

// ---------------------------------------------------------------------------
// K4: per-batch stable exclusive prefix sum via wave scans (2 syncs)
// ---------------------------------------------------------------------------
__global__ __launch_bounds__(1024) void k4_scan(
    const int* __restrict__ keep, int* __restrict__ pos,
    int* __restrict__ counts, double* __restrict__ logprob) {
  __shared__ int wsum[16];
  const int b = blockIdx.x, tid = threadIdx.x;
  const int lane = tid & 63, wave = tid >> 6;
  const size_t base = (size_t)b * Sn + (size_t)tid * 8;
  const int4 kk0 = *(const int4*)(keep + base);
  const int4 kk1 = *(const int4*)(keep + base + 4);
  int v[8] = {kk0.x, kk0.y, kk0.z, kk0.w, kk1.x, kk1.y, kk1.z, kk1.w};
  int pref[8], tot = 0;
#pragma unroll
  for (int j = 0; j < 8; ++j) {
    pref[j] = tot;
    tot += v[j];
  }
  int x = tot;
#pragma unroll
  for (int m = 1; m < 64; m <<= 1) {
    const int y = __shfl_up(x, m, 64);
    if (lane >= m) x += y;
  }
  if (lane == 63) wsum[wave] = x;
  __syncthreads();
  int wp = 0;
  for (int w = 0; w < wave; ++w) wp += wsum[w];
  const int excl = wp + x - tot;
  int4 o0, o1;
  o0.x = excl + pref[0]; o0.y = excl + pref[1]; o0.z = excl + pref[2]; o0.w = excl + pref[3];
  o1.x = excl + pref[4]; o1.y = excl + pref[5]; o1.z = excl + pref[6]; o1.w = excl + pref[7];
  *(int4*)(pos + base) = o0;
  *(int4*)(pos + base + 4) = o1;
  if (tid == 0) {
    int total = 0;
    for (int w = 0; w < 16; ++w) total += wsum[w];
    counts[b] = total;
    const double n = (double)Sn, k = (double)total;
    logprob[b] = lgamma(n + 1.0) - lgamma(k + 1.0) - lgamma(n - k + 1.0) +
                 k * log(0.2) + (n - k) * log1p(-0.2);
  }
}

// ---------------------------------------------------------------------------
// K5: scatter kept rows h = hidden*inv_norm to out[b,pos]; zero rows >= count
// ---------------------------------------------------------------------------
__global__ __launch_bounds__(256) void k5_scatter(
    const float* __restrict__ hidden, const double* __restrict__ inv_norm,
    const int* __restrict__ keep, const int* __restrict__ pos,
    const int* __restrict__ counts, const double* __restrict__ logprob,
    float* __restrict__ out) {
  const int b = blockIdx.x / CHUNKS;
  const int chunk = blockIdx.x % CHUNKS;
  const int wave = threadIdx.x >> 6, lane = threadIdx.x & 63;
  const int cnt = counts[b];
  const int sbase = chunk * TOK_PER_BLOCK + wave * TOK_PER_WAVE;
  const float* hb = hidden + (size_t)b * Sn * Dn;
  float* ob = out + (size_t)b * Sn * Dn;
  for (int t = 0; t < TOK_PER_WAVE; ++t) {
    const int s = sbase + t;
    const size_t tok = (size_t)b * Sn + s;
    if (s >= cnt) {
      float4* orow = (float4*)(ob + (size_t)s * Dn);
      const float4 z = make_float4(0.f, 0.f, 0.f, 0.f);
      orow[lane] = z;
      orow[64 + lane] = z;
    }
    if (keep[tok]) {
      const int p = pos[tok];
      const double inv = inv_norm[tok];
      const float4* row = (const float4*)(hb + (size_t)s * Dn);
      float4 a = row[lane], c = row[64 + lane];
      a.x = (float)((double)a.x * inv); a.y = (float)((double)a.y * inv);
      a.z = (float)((double)a.z * inv); a.w = (float)((double)a.w * inv);
      c.x = (float)((double)c.x * inv); c.y = (float)((double)c.y * inv);
      c.z = (float)((double)c.z * inv); c.w = (float)((double)c.w * inv);
      float4* orow = (float4*)(ob + (size_t)p * Dn);
      orow[lane] = a;
      orow[64 + lane] = c;
    }
  }
  if (blockIdx.x == 0 && threadIdx.x == 0) {
    double sm = 0.0;
    for (int i = 0; i < Bn; ++i) sm += logprob[i];
    out[(size_t)Bn * Sn * Dn] = (float)(-(sm / (double)Bn) / (double)Sn);
  }
}

// ---------------------------------------------------------------------------
extern "C" void kernel_launch(void* const* d_in, const int* in_sizes, int n_in,
                              void* d_out, int out_size, void* d_ws, size_t ws_size,
                              hipStream_t stream) {
  const float* hidden = (const float*)d_in[0];
  const float* Wq = (const float*)d_in[1];
  const float* Wk = (const float*)d_in[2];
  const float* noise = (const float*)d_in[3];
  float* out = (float*)d_out;

  char* ws = (char*)d_ws;
  double* hsum = (double*)(ws);                               // 65536
  double* u = (double*)(ws + 65536);                          // 65536
  double* inv_nrm = (double*)(ws + 131072);                   // 1048576
  int* keep = (int*)(ws + 131072 + 1048576);                  // 524288
  int* pos = (int*)(ws + 131072 + 1048576 + 524288);          // 524288
  int* counts = (int*)(ws + 131072 + 1048576 + 2 * 524288);   // 256
  double* logprob = (double*)(ws + 131072 + 1048576 + 2 * 524288 + 256);

  hipMemsetAsync(hsum, 0, Bn * Dn * sizeof(double), stream);

  k1_norm_hsum<<<Bn * CHUNKS, 256, 0, stream>>>(hidden, inv_nrm, hsum);
  k2_u<<<Bn, 512, 0, stream>>>(Wq, Wk, hsum, u);
  k3_scores<<<Bn * CHUNKS, 256, 0, stream>>>(hidden, inv_nrm, u, noise, keep);
  k4_scan<<<Bn, 1024, 0, stream>>>(keep, pos, counts, logprob);
  k5_scatter<<<Bn * CHUNKS, 256, 0, stream>>>(hidden, inv_nrm, keep, pos, counts,
                                              logprob, out);
}

// Round 3
// 573.175 us; speedup vs baseline: 1.1604x; 1.0564x over previous
//
#include <hip/hip_runtime.h>
#include <math.h>

#define Bn 16
#define Sn 8192
#define Dn 512
#define CHUNKS 64
#define TOK_PER_BLOCK (Sn / CHUNKS)      // 128 tokens per block
#define TOK_PER_WAVE (TOK_PER_BLOCK / 4) // 32 tokens per wave (4 waves/block)

__device__ __forceinline__ double dot8sq(const float4& a, const float4& c) {
  return (double)a.x * a.x + (double)a.y * a.y + (double)a.z * a.z +
         (double)a.w * a.w + (double)c.x * c.x + (double)c.y * c.y +
         (double)c.z * c.z + (double)c.w * c.w;
}

// ---------------------------------------------------------------------------
// K1: per-token L2 norm (f64) -> inv_norm; hsum[b] = sum_s h[b,s] (f64)
// Software-pipelined: next 4 tokens' loads issued before current butterfly.
// ---------------------------------------------------------------------------
__global__ __launch_bounds__(256) void k1_norm_hsum(
    const float* __restrict__ hidden, double* __restrict__ inv_norm,
    double* __restrict__ hsum) {
  __shared__ double part[4][Dn];  // 16 KB
  const int b = blockIdx.x / CHUNKS;
  const int chunk = blockIdx.x % CHUNKS;
  const int wave = threadIdx.x >> 6;
  const int lane = threadIdx.x & 63;

  double acc[8] = {0., 0., 0., 0., 0., 0., 0., 0.};
  const int sbase = chunk * TOK_PER_BLOCK + wave * TOK_PER_WAVE;
  const float* hb = hidden + (size_t)b * Sn * Dn;

  float4 cur[8];
#pragma unroll
  for (int j = 0; j < 4; ++j) {
    const float4* r = (const float4*)(hb + (size_t)(sbase + j) * Dn);
    cur[2 * j] = r[lane];
    cur[2 * j + 1] = r[64 + lane];
  }

  for (int t0 = 0; t0 < TOK_PER_WAVE; t0 += 4) {
    const bool more = (t0 + 4) < TOK_PER_WAVE;
    float4 nxt[8];
    if (more) {
#pragma unroll
      for (int j = 0; j < 4; ++j) {
        const float4* r = (const float4*)(hb + (size_t)(sbase + t0 + 4 + j) * Dn);
        nxt[2 * j] = r[lane];
        nxt[2 * j + 1] = r[64 + lane];
      }
    }
    double ss[4];
#pragma unroll
    for (int j = 0; j < 4; ++j) ss[j] = dot8sq(cur[2 * j], cur[2 * j + 1]);
#pragma unroll
    for (int m = 32; m >= 1; m >>= 1) {
#pragma unroll
      for (int j = 0; j < 4; ++j) ss[j] += __shfl_xor(ss[j], m, 64);
    }
    double inv[4];
#pragma unroll
    for (int j = 0; j < 4; ++j) inv[j] = 1.0 / fmax(sqrt(ss[j]), 1e-12);
    if (lane < 4) {
      const double iv = (lane == 0) ? inv[0] : (lane == 1) ? inv[1]
                       : (lane == 2) ? inv[2] : inv[3];
      inv_norm[(size_t)b * Sn + sbase + t0 + lane] = iv;
    }
#pragma unroll
    for (int j = 0; j < 4; ++j) {
      acc[0] += (double)cur[2 * j].x * inv[j];
      acc[1] += (double)cur[2 * j].y * inv[j];
      acc[2] += (double)cur[2 * j].z * inv[j];
      acc[3] += (double)cur[2 * j].w * inv[j];
      acc[4] += (double)cur[2 * j + 1].x * inv[j];
      acc[5] += (double)cur[2 * j + 1].y * inv[j];
      acc[6] += (double)cur[2 * j + 1].z * inv[j];
      acc[7] += (double)cur[2 * j + 1].w * inv[j];
    }
    if (more) {
#pragma unroll
      for (int j = 0; j < 8; ++j) cur[j] = nxt[j];
    }
  }
  const int d0 = lane * 4;
#pragma unroll
  for (int k = 0; k < 4; ++k) {
    part[wave][d0 + k] = acc[k];
    part[wave][256 + d0 + k] = acc[4 + k];
  }
  __syncthreads();
  for (int i = threadIdx.x; i < Dn; i += 256) {
    const double v = part[0][i] + part[1][i] + part[2][i] + part[3][i];
    atomicAdd(&hsum[b * Dn + i], v);
  }
}

// ---------------------------------------------------------------------------
// K2a: ks[b] = Wk * hsum[b]  (f64). 256 blocks, wave-per-row, coalesced.
// ---------------------------------------------------------------------------
__global__ __launch_bounds__(256) void k2a_ks(
    const float* __restrict__ Wk, const double* __restrict__ hsum,
    double* __restrict__ ks) {
  __shared__ double hl[Dn];
  const int b = blockIdx.x >> 4;    // 16 row-groups per batch
  const int rg = blockIdx.x & 15;
  const int tid = threadIdx.x, wave = tid >> 6, lane = tid & 63;
  for (int i = tid; i < Dn; i += 256) hl[i] = hsum[b * Dn + i];
  __syncthreads();
#pragma unroll
  for (int rp = 0; rp < 8; rp += 2) {
    const int row0 = rg * 32 + wave * 8 + rp;
    const int row1 = row0 + 1;
    const float* w0 = Wk + (size_t)row0 * Dn;
    const float* w1 = Wk + (size_t)row1 * Dn;
    double s0 = 0., s1 = 0.;
#pragma unroll
    for (int j = 0; j < 8; ++j) {
      const int e = lane + 64 * j;           // coalesced across lanes
      s0 += (double)w0[e] * hl[e];
      s1 += (double)w1[e] * hl[e];
    }
#pragma unroll
    for (int m = 32; m >= 1; m >>= 1) {
      s0 += __shfl_xor(s0, m, 64);
      s1 += __shfl_xor(s1, m, 64);
    }
    if (lane == 0) ks[b * Dn + row0] = s0;
    if (lane == 1) ks[b * Dn + row1] = s1;
  }
}

// ---------------------------------------------------------------------------
// K2b: u[b] = Wq^T * ks[b]  (f64). 64 blocks, coalesced column reads.
// ---------------------------------------------------------------------------
__global__ __launch_bounds__(128) void k2b_u(
    const float* __restrict__ Wq, const double* __restrict__ ks,
    double* __restrict__ u) {
  __shared__ double kl[Dn];
  const int b = blockIdx.x >> 2;
  const int g = blockIdx.x & 3;
  const int tid = threadIdx.x;
  for (int i = tid; i < Dn; i += 128) kl[i] = ks[b * Dn + i];
  __syncthreads();
  const int e = g * 128 + tid;
  double p0 = 0., p1 = 0., p2 = 0., p3 = 0.;
  for (int d = 0; d < Dn; d += 4) {
    p0 += (double)Wq[(size_t)(d + 0) * Dn + e] * kl[d + 0];
    p1 += (double)Wq[(size_t)(d + 1) * Dn + e] * kl[d + 1];
    p2 += (double)Wq[(size_t)(d + 2) * Dn + e] * kl[d + 2];
    p3 += (double)Wq[(size_t)(d + 3) * Dn + e] * kl[d + 3];
  }
  u[b * Dn + e] = (p0 + p1) + (p2 + p3);
}

// ---------------------------------------------------------------------------
// K3: scores (f64) + keep decision; u in registers; 8 tokens per iteration
// ---------------------------------------------------------------------------
__global__ __launch_bounds__(256) void k3_scores(
    const float* __restrict__ hidden, const double* __restrict__ inv_norm,
    const double* __restrict__ u, const float* __restrict__ noise,
    int* __restrict__ keep) {
  __shared__ double ul[Dn];
  const int b = blockIdx.x / CHUNKS;
  const int chunk = blockIdx.x % CHUNKS;
  for (int i = threadIdx.x; i < Dn; i += 256) ul[i] = u[b * Dn + i];
  __syncthreads();
  const int wave = threadIdx.x >> 6, lane = threadIdx.x & 63;
  const int d0 = lane * 4;
  const double u0 = ul[d0 + 0], u1 = ul[d0 + 1], u2 = ul[d0 + 2], u3 = ul[d0 + 3];
  const double u4 = ul[256 + d0 + 0], u5 = ul[256 + d0 + 1];
  const double u6 = ul[256 + d0 + 2], u7 = ul[256 + d0 + 3];
  const int sbase = chunk * TOK_PER_BLOCK + wave * TOK_PER_WAVE;
  const float* hb = hidden + (size_t)b * Sn * Dn;

  for (int t0 = 0; t0 < TOK_PER_WAVE; t0 += 8) {
    double dv[8];
#pragma unroll
    for (int j = 0; j < 8; ++j) {
      const float4* r = (const float4*)(hb + (size_t)(sbase + t0 + j) * Dn);
      const float4 a = r[lane], c = r[64 + lane];
      dv[j] = (double)a.x * u0 + (double)a.y * u1 + (double)a.z * u2 +
              (double)a.w * u3 + (double)c.x * u4 + (double)c.y * u5 +
              (double)c.z * u6 + (double)c.w * u7;
    }
#pragma unroll
    for (int m = 32; m >= 1; m >>= 1) {
#pragma unroll
      for (int j = 0; j < 8; ++j) dv[j] += __shfl_xor(dv[j], m, 64);
    }
    if (lane < 8) {
      double dj = dv[0];
#pragma unroll
      for (int j = 1; j < 8; ++j) dj = (lane == j) ? dv[j] : dj;
      const size_t tok = (size_t)b * Sn + sbase + t0 + lane;
      const double nv = (double)noise[tok];
      const double x = 0.125 * inv_norm[tok] * dj + log(nv) - log1p(-nv);
      keep[tok] = (x > 0.0) ? 1 : 0;
    }
  }
}

// ---------------------------------------------------------------------------
// K4: per-batch stable exclusive prefix sum via wave scans (2 syncs)
// ---------------------------------------------------------------------------
__global__ __launch_bounds__(1024) void k4_scan(
    const int* __restrict__ keep, int* __restrict__ pos,
    int* __restrict__ counts, double* __restrict__ logprob) {
  __shared__ int wsum[16];
  const int b = blockIdx.x, tid = threadIdx.x;
  const int lane = tid & 63, wave = tid >> 6;
  const size_t base = (size_t)b * Sn + (size_t)tid * 8;
  const int4 kk0 = *(const int4*)(keep + base);
  const int4 kk1 = *(const int4*)(keep + base + 4);
  int v[8] = {kk0.x, kk0.y, kk0.z, kk0.w, kk1.x, kk1.y, kk1.z, kk1.w};
  int pref[8], tot = 0;
#pragma unroll
  for (int j = 0; j < 8; ++j) {
    pref[j] = tot;
    tot += v[j];
  }
  int x = tot;
#pragma unroll
  for (int m = 1; m < 64; m <<= 1) {
    const int y = __shfl_up(x, m, 64);
    if (lane >= m) x += y;
  }
  if (lane == 63) wsum[wave] = x;
  __syncthreads();
  int wp = 0;
  for (int w = 0; w < wave; ++w) wp += wsum[w];
  const int excl = wp + x - tot;
  int4 o0, o1;
  o0.x = excl + pref[0]; o0.y = excl + pref[1]; o0.z = excl + pref[2]; o0.w = excl + pref[3];
  o1.x = excl + pref[4]; o1.y = excl + pref[5]; o1.z = excl + pref[6]; o1.w = excl + pref[7];
  *(int4*)(pos + base) = o0;
  *(int4*)(pos + base + 4) = o1;
  if (tid == 0) {
    int total = 0;
    for (int w = 0; w < 16; ++w) total += wsum[w];
    counts[b] = total;
    const double n = (double)Sn, k = (double)total;
    logprob[b] = lgamma(n + 1.0) - lgamma(k + 1.0) - lgamma(n - k + 1.0) +
                 k * log(0.2) + (n - k) * log1p(-0.2);
  }
}

// ---------------------------------------------------------------------------
// K5: scatter kept rows to out[b,pos]; zero rows >= count; loss scalar.
// Metadata preloaded per wave (32 tokens) and broadcast via shuffles.
// ---------------------------------------------------------------------------
__global__ __launch_bounds__(256) void k5_scatter(
    const float* __restrict__ hidden, const double* __restrict__ inv_norm,
    const int* __restrict__ keep, const int* __restrict__ pos,
    const int* __restrict__ counts, const double* __restrict__ logprob,
    float* __restrict__ out) {
  const int b = blockIdx.x / CHUNKS;
  const int chunk = blockIdx.x % CHUNKS;
  const int wave = threadIdx.x >> 6, lane = threadIdx.x & 63;
  const int cnt = counts[b];
  const int sbase = chunk * TOK_PER_BLOCK + wave * TOK_PER_WAVE;
  const size_t tbase = (size_t)b * Sn + sbase;
  const float* hb = hidden + (size_t)b * Sn * Dn;
  float* ob = out + (size_t)b * Sn * Dn;

  int mk = 0, mp = 0;
  double mi = 0.0;
  if (lane < 32) {
    mk = keep[tbase + lane];
    mp = pos[tbase + lane];
    mi = inv_norm[tbase + lane];
  }
  const float4 z = make_float4(0.f, 0.f, 0.f, 0.f);

  for (int t0 = 0; t0 < TOK_PER_WAVE; t0 += 4) {
    int kk[4], pp[4], ss[4];
    double iv[4];
#pragma unroll
    for (int j = 0; j < 4; ++j) {
      kk[j] = __shfl(mk, t0 + j, 64);
      pp[j] = __shfl(mp, t0 + j, 64);
      iv[j] = __shfl(mi, t0 + j, 64);
      ss[j] = sbase + t0 + j;
    }
    // zero-fill rows past count (no load dependency — issues immediately)
#pragma unroll
    for (int j = 0; j < 4; ++j) {
      if (ss[j] >= cnt) {
        float4* orow = (float4*)(ob + (size_t)ss[j] * Dn);
        orow[lane] = z;
        orow[64 + lane] = z;
      }
    }
    // load phase for kept rows (wave-uniform branches; loads overlap)
    float4 a[4], c[4];
#pragma unroll
    for (int j = 0; j < 4; ++j) {
      if (kk[j]) {
        const float4* r = (const float4*)(hb + (size_t)ss[j] * Dn);
        a[j] = r[lane];
        c[j] = r[64 + lane];
      }
    }
    // scale + store phase
#pragma unroll
    for (int j = 0; j < 4; ++j) {
      if (kk[j]) {
        float4 aa = a[j], cc = c[j];
        const double v = iv[j];
        aa.x = (float)((double)aa.x * v); aa.y = (float)((double)aa.y * v);
        aa.z = (float)((double)aa.z * v); aa.w = (float)((double)aa.w * v);
        cc.x = (float)((double)cc.x * v); cc.y = (float)((double)cc.y * v);
        cc.z = (float)((double)cc.z * v); cc.w = (float)((double)cc.w * v);
        float4* orow = (float4*)(ob + (size_t)pp[j] * Dn);
        orow[lane] = aa;
        orow[64 + lane] = cc;
      }
    }
  }
  if (blockIdx.x == 0 && threadIdx.x == 0) {
    double sm = 0.0;
    for (int i = 0; i < Bn; ++i) sm += logprob[i];
    out[(size_t)Bn * Sn * Dn] = (float)(-(sm / (double)Bn) / (double)Sn);
  }
}

// ---------------------------------------------------------------------------
extern "C" void kernel_launch(void* const* d_in, const int* in_sizes, int n_in,
                              void* d_out, int out_size, void* d_ws, size_t ws_size,
                              hipStream_t stream) {
  const float* hidden = (const float*)d_in[0];
  const float* Wq = (const float*)d_in[1];
  const float* Wk = (const float*)d_in[2];
  const float* noise = (const float*)d_in[3];
  float* out = (float*)d_out;

  char* ws = (char*)d_ws;
  double* hsum = (double*)(ws);                   // 65536
  double* u = (double*)(ws + 65536);              // 65536
  double* ks = (double*)(ws + 131072);            // 65536
  double* inv_nrm = (double*)(ws + 196608);       // 1048576
  int* keep = (int*)(ws + 1245184);               // 524288
  int* pos = (int*)(ws + 1769472);                // 524288
  int* counts = (int*)(ws + 2293760);             // 256
  double* logprob = (double*)(ws + 2294016);      // 128

  hipMemsetAsync(hsum, 0, Bn * Dn * sizeof(double), stream);

  k1_norm_hsum<<<Bn * CHUNKS, 256, 0, stream>>>(hidden, inv_nrm, hsum);
  k2a_ks<<<Bn * 16, 256, 0, stream>>>(Wk, hsum, ks);
  k2b_u<<<Bn * 4, 128, 0, stream>>>(Wq, ks, u);
  k3_scores<<<Bn * CHUNKS, 256, 0, stream>>>(hidden, inv_nrm, u, noise, keep);
  k4_scan<<<Bn, 1024, 0, stream>>>(keep, pos, counts, logprob);
  k5_scatter<<<Bn * CHUNKS, 256, 0, stream>>>(hidden, inv_nrm, keep, pos, counts,
                                              logprob, out);
}